// Round 7
// baseline (967.903 us; speedup 1.0000x reference)
//
#include <hip/hip_runtime.h>
#include <hip/hip_bf16.h>
#include <math.h>

#define D_MODEL 1024
#define NH 16
#define DK 64
#define MF 256
#define LSEQ 4096
#define NB 2
#define BL (NB*LSEQ)   // 8192

typedef __attribute__((ext_vector_type(8))) short short8;
typedef __attribute__((ext_vector_type(4))) float f32x4;

static __device__ __forceinline__ unsigned short f2bf(float x) {
    return __builtin_bit_cast(unsigned short, __float2bfloat16(x));
}

// ---------------------------------------------------------------------------
// W[k][n] fp32 -> Wt[n][k] bf16 (transpose + convert), 32x32 tiles
// ---------------------------------------------------------------------------
__global__ __launch_bounds__(256)
void wcvt_transpose(const float* __restrict__ W, unsigned short* __restrict__ Wt)
{
    __shared__ float tile[32][33];
    const int t  = threadIdx.x;
    const int k0 = blockIdx.x * 32;
    const int n0 = blockIdx.y * 32;
    const int r  = t >> 3;
    const int c4 = (t & 7) * 4;
    *(float4*)&tile[r][c4] = *(const float4*)&W[(size_t)(k0 + r) * D_MODEL + n0 + c4];
    __syncthreads();
    ushort4 o;
    o.x = f2bf(tile[c4 + 0][r]);
    o.y = f2bf(tile[c4 + 1][r]);
    o.z = f2bf(tile[c4 + 2][r]);
    o.w = f2bf(tile[c4 + 3][r]);
    *(ushort4*)&Wt[(size_t)(n0 + r) * D_MODEL + k0 + c4] = o;
}

// ---------------------------------------------------------------------------
// bf16 MFMA GEMM: C[8192][1024] = A_f32[8192][1024] @ Wt_bf16[n][k]^T (+bias)
// MODE 0: head-major (B,H,L,DK) write with scale; MODE 1: row-major + bias.
// 128x128 tile, 4 waves, each wave 64x64 = 4x4 frags of 16x16x32.
// A converted fp32->bf16 during reg-staging; B already bf16 (pre-transposed).
// LDS row stride 40 ushorts (80 B): 16B-aligned, <=2-way bank alias on reads.
// ---------------------------------------------------------------------------
#define GBK 32
#define LDST 40

template<int MODE>
__global__ __launch_bounds__(256)
void gemm_bf16(const float* __restrict__ A, const unsigned short* __restrict__ Bt,
               const float* __restrict__ bias, float* __restrict__ out, float scale)
{
    __shared__ unsigned short As[128][LDST];   // [m][k]
    __shared__ unsigned short Bs[128][LDST];   // [n][k]
    const int t    = threadIdx.x;
    const int lane = t & 63;
    const int w    = t >> 6;
    const int wrow = (w >> 1) * 64;
    const int wcol = (w & 1) * 64;
    const int m0   = blockIdx.x * 128;
    const int n0   = blockIdx.y * 128;

    const int sr  = t & 127;    // staging row (m for A, n for B)
    const int skh = t >> 7;     // k-half: 16 elements

    f32x4 acc[4][4];
    #pragma unroll
    for (int i = 0; i < 4; i++)
        #pragma unroll
        for (int j = 0; j < 4; j++)
            acc[i][j] = (f32x4){0.f, 0.f, 0.f, 0.f};

    const float*          ap = A  + (size_t)(m0 + sr) * D_MODEL + skh * 16;
    const unsigned short* bp = Bt + (size_t)(n0 + sr) * D_MODEL + skh * 16;

    for (int k0 = 0; k0 < D_MODEL; k0 += GBK) {
        // stage A: 16 fp32 -> 16 bf16 -> 2x ds_write_b128
        float4 a0 = *(const float4*)(ap + k0 + 0);
        float4 a1 = *(const float4*)(ap + k0 + 4);
        float4 a2 = *(const float4*)(ap + k0 + 8);
        float4 a3 = *(const float4*)(ap + k0 + 12);
        short8 va0, va1;
        va0[0] = (short)f2bf(a0.x); va0[1] = (short)f2bf(a0.y);
        va0[2] = (short)f2bf(a0.z); va0[3] = (short)f2bf(a0.w);
        va0[4] = (short)f2bf(a1.x); va0[5] = (short)f2bf(a1.y);
        va0[6] = (short)f2bf(a1.z); va0[7] = (short)f2bf(a1.w);
        va1[0] = (short)f2bf(a2.x); va1[1] = (short)f2bf(a2.y);
        va1[2] = (short)f2bf(a2.z); va1[3] = (short)f2bf(a2.w);
        va1[4] = (short)f2bf(a3.x); va1[5] = (short)f2bf(a3.y);
        va1[6] = (short)f2bf(a3.z); va1[7] = (short)f2bf(a3.w);
        *(short8*)&As[sr][skh * 16 + 0] = va0;
        *(short8*)&As[sr][skh * 16 + 8] = va1;
        // stage B: already bf16, 2x 16B global -> 2x ds_write_b128
        short8 vb0 = *(const short8*)(bp + k0 + 0);
        short8 vb1 = *(const short8*)(bp + k0 + 8);
        *(short8*)&Bs[sr][skh * 16 + 0] = vb0;
        *(short8*)&Bs[sr][skh * 16 + 8] = vb1;
        __syncthreads();

        short8 af[4], bfr[4];
        #pragma unroll
        for (int i = 0; i < 4; i++) {
            af[i]  = *(const short8*)&As[wrow + i * 16 + (lane & 15)][(lane >> 4) * 8];
            bfr[i] = *(const short8*)&Bs[wcol + i * 16 + (lane & 15)][(lane >> 4) * 8];
        }
        #pragma unroll
        for (int mr = 0; mr < 4; mr++)
            #pragma unroll
            for (int nc = 0; nc < 4; nc++)
                acc[mr][nc] = __builtin_amdgcn_mfma_f32_16x16x32_bf16(
                    af[mr], bfr[nc], acc[mr][nc], 0, 0, 0);
        __syncthreads();
    }

    // epilogue: C/D frag mapping col=lane&15, row=(lane>>4)*4+reg (m89/m91)
    const int crow = (lane >> 4) * 4;
    const int ccol = lane & 15;
    #pragma unroll
    for (int nc = 0; nc < 4; nc++) {
        const int gcol = n0 + wcol + nc * 16 + ccol;
        const float bb = bias[gcol];
        #pragma unroll
        for (int mr = 0; mr < 4; mr++) {
            #pragma unroll
            for (int r = 0; r < 4; r++) {
                const int grow = m0 + wrow + mr * 16 + crow + r;
                const float v = acc[mr][nc][r] + bb;
                if (MODE == 0) {
                    const int b = grow >> 12;          // L = 4096
                    const int l = grow & (LSEQ - 1);
                    const int h = gcol >> 6;
                    const int c = gcol & 63;
                    out[((size_t)(b * NH + h) * LSEQ + l) * DK + c] = v * scale;
                } else {
                    out[(size_t)grow * D_MODEL + gcol] = v;
                }
            }
        }
    }
}

// ---------------------------------------------------------------------------
// Kf = exp(kh_scaled @ proj^T); KV += Kf^T @ vh; Z += colsum(Kf)
// One block = one (b,h) x one 256-row L-chunk. Thread t owns feature row m=t.
// ---------------------------------------------------------------------------
__global__ __launch_bounds__(256)
void kv_partial(const float* __restrict__ kh, const float* __restrict__ vh,
                const float* __restrict__ proj, float* __restrict__ KVp,
                float* __restrict__ Zp)
{
    const int bh    = blockIdx.x;        // 0..31 = b*16+h
    const int h     = bh & (NH - 1);
    const int chunk = blockIdx.y;        // 0..15
    const int t     = threadIdx.x;       // m index

    __shared__ float khs[32][64];
    __shared__ float vhs[32][64];

    float4 pr[16];
    {
        const float4* pp = (const float4*)(proj + ((size_t)h * MF + t) * DK);
        #pragma unroll
        for (int i = 0; i < 16; i++) pr[i] = pp[i];
    }
    float acc[64];
    #pragma unroll
    for (int d = 0; d < 64; d++) acc[d] = 0.f;
    float zacc = 0.f;

    const size_t base = ((size_t)bh * LSEQ + (size_t)chunk * 256) * DK;
    const float* khb = kh + base;
    const float* vhb = vh + base;

    for (int s0 = 0; s0 < 256; s0 += 32) {
        #pragma unroll
        for (int i = 0; i < 2; i++) {
            int idx = t + 256 * i;
            int r  = idx >> 4;
            int c4 = (idx & 15) * 4;
            *(float4*)&khs[r][c4] = *(const float4*)&khb[(size_t)(s0 + r) * DK + c4];
            *(float4*)&vhs[r][c4] = *(const float4*)&vhb[(size_t)(s0 + r) * DK + c4];
        }
        __syncthreads();
        #pragma unroll 4
        for (int l = 0; l < 32; l++) {
            float rf = 0.f;
            const float4* kr = (const float4*)khs[l];
            #pragma unroll
            for (int i = 0; i < 16; i++) {
                float4 k4 = kr[i];   // all-lane broadcast LDS read
                rf += k4.x * pr[i].x + k4.y * pr[i].y + k4.z * pr[i].z + k4.w * pr[i].w;
            }
            float kf = __expf(rf);
            zacc += kf;
            const float4* vr = (const float4*)vhs[l];
            #pragma unroll
            for (int i = 0; i < 16; i++) {
                float4 v4 = vr[i];
                acc[4*i+0] += kf * v4.x;
                acc[4*i+1] += kf * v4.y;
                acc[4*i+2] += kf * v4.z;
                acc[4*i+3] += kf * v4.w;
            }
        }
        __syncthreads();
    }

    float* o = KVp + ((size_t)chunk * 32 + bh) * (MF * DK) + (size_t)t * DK;
    #pragma unroll
    for (int i = 0; i < 16; i++)
        ((float4*)o)[i] = make_float4(acc[4*i], acc[4*i+1], acc[4*i+2], acc[4*i+3]);
    Zp[((size_t)chunk * 32 + bh) * MF + t] = zacc;
}

// Reduce 16 L-chunk partials -> KV (32*256*64) and Z (32*256)
__global__ __launch_bounds__(256)
void kv_reduce(const float* __restrict__ KVp, const float* __restrict__ Zp,
               float* __restrict__ KV, float* __restrict__ Z)
{
    const size_t i = (size_t)blockIdx.x * 256 + threadIdx.x;  // < 524288
    float s = 0.f;
    #pragma unroll
    for (int c = 0; c < 16; c++) s += KVp[(size_t)c * 524288 + i];
    KV[i] = s;
    if (i < 32 * MF) {
        float z = 0.f;
        #pragma unroll
        for (int c = 0; c < 16; c++) z += Zp[(size_t)c * 8192 + i];
        Z[i] = z;
    }
}

// ---------------------------------------------------------------------------
// Qf = exp(qh_scaled @ proj^T)/sqrt(M); num = Qf@KV; den = Qf@Z + eps;
// attn[b][l][h*64+dk] = num/den  (written in (B,L,D) layout)
// ---------------------------------------------------------------------------
__global__ __launch_bounds__(256)
void qnum(const float* __restrict__ qh, const float* __restrict__ proj,
          const float* __restrict__ KV, const float* __restrict__ Z,
          float* __restrict__ attn)
{
    const int bh = blockIdx.x;
    const int h  = bh & (NH - 1);
    const int b  = bh >> 4;
    const int l0 = blockIdx.y * 64;
    const int t  = threadIdx.x;

    __shared__ float qhs[32][64];
    __shared__ float qfs[32][MF + 1];
    __shared__ float Zs[MF];

    float4 pr[16];
    {
        const float4* pp = (const float4*)(proj + ((size_t)h * MF + t) * DK);
        #pragma unroll
        for (int i = 0; i < 16; i++) pr[i] = pp[i];
    }
    Zs[t] = Z[(size_t)bh * MF + t];

    const float* qhb = qh + ((size_t)bh * LSEQ + l0) * DK;
    const float* KVb = KV + (size_t)bh * (MF * DK);
    const int lo  = t >> 3;
    const int dk0 = (t & 7) * 8;

    for (int s0 = 0; s0 < 64; s0 += 32) {
        #pragma unroll
        for (int i = 0; i < 2; i++) {
            int idx = t + 256 * i;
            int r  = idx >> 4;
            int c4 = (idx & 15) * 4;
            *(float4*)&qhs[r][c4] = *(const float4*)&qhb[(size_t)(s0 + r) * DK + c4];
        }
        __syncthreads();
        #pragma unroll 4
        for (int l = 0; l < 32; l++) {
            float rf = 0.f;
            const float4* qr = (const float4*)qhs[l];
            #pragma unroll
            for (int i = 0; i < 16; i++) {
                float4 q4 = qr[i];
                rf += q4.x * pr[i].x + q4.y * pr[i].y + q4.z * pr[i].z + q4.w * pr[i].w;
            }
            qfs[l][t] = __expf(rf) * 0.0625f;   // 1/sqrt(M) = 1/16
        }
        __syncthreads();

        float a0=0,a1=0,a2=0,a3=0,a4=0,a5=0,a6=0,a7=0, den=0;
        #pragma unroll 4
        for (int m = 0; m < MF; m++) {
            float qf = qfs[lo][m];
            den += qf * Zs[m];
            float4 k1 = *(const float4*)(KVb + (size_t)m * DK + dk0);
            float4 k2 = *(const float4*)(KVb + (size_t)m * DK + dk0 + 4);
            a0 += qf * k1.x; a1 += qf * k1.y; a2 += qf * k1.z; a3 += qf * k1.w;
            a4 += qf * k2.x; a5 += qf * k2.y; a6 += qf * k2.z; a7 += qf * k2.w;
        }
        float inv = 1.f / (den + 1e-6f);
        float* op = attn + (((size_t)b * LSEQ + (l0 + s0 + lo)) * NH + h) * DK + dk0;
        *(float4*)op       = make_float4(a0 * inv, a1 * inv, a2 * inv, a3 * inv);
        *(float4*)(op + 4) = make_float4(a4 * inv, a5 * inv, a6 * inv, a7 * inv);
        __syncthreads();
    }
}

// ---------------------------------------------------------------------------
extern "C" void kernel_launch(void* const* d_in, const int* in_sizes, int n_in,
                              void* d_out, int out_size, void* d_ws, size_t ws_size,
                              hipStream_t stream)
{
    (void)in_sizes; (void)n_in; (void)out_size;
    const float* Q    = (const float*)d_in[0];
    const float* K    = (const float*)d_in[1];
    const float* V    = (const float*)d_in[2];
    const float* Wq   = (const float*)d_in[3];
    const float* bq   = (const float*)d_in[4];
    const float* Wk   = (const float*)d_in[5];
    const float* bk   = (const float*)d_in[6];
    const float* Wv   = (const float*)d_in[7];
    const float* bv   = (const float*)d_in[8];
    const float* Wo   = (const float*)d_in[9];
    const float* bo   = (const float*)d_in[10];
    const float* proj = (const float*)d_in[11];
    float* out = (float*)d_out;
    float* ws  = (float*)d_ws;

    // workspace (float offsets), peak ~111.7 MB:
    float* kh   = ws;                  // 8388608  (B,H,L,DK) pre-scaled 1/8; -> attn later
    float* vh   = ws +  8388608;       // 8388608  (B,H,L,DK)
    float* KVp  = ws + 16777216;       // 8388608  (16 chunks x 524288); -> qh later
    float* Zp   = ws + 25165824;       // 131072
    float* KV   = ws + 25296896;       // 524288
    float* Z    = ws + 25821184;       // 8192
    unsigned short* Wtk = (unsigned short*)(ws + 25829376);  // 1M bf16 = 524288 fl
    unsigned short* Wtv = (unsigned short*)(ws + 26353664);
    unsigned short* Wtq = (unsigned short*)(ws + 26877952);
    unsigned short* Wto = (unsigned short*)(ws + 27402240);
    float* qh   = KVp;                 // KVp dead after kv_reduce
    float* attn = kh;                  // kh dead after kv_partial
    if (ws_size < (size_t)27926528 * sizeof(float)) return;  // guard

    const dim3 gw(32, 32);             // W transpose tiles
    const dim3 gg(BL / 128, D_MODEL / 128);  // 64 x 8
    hipLaunchKernelGGL(wcvt_transpose, gw, dim3(256), 0, stream, Wk, Wtk);
    hipLaunchKernelGGL(wcvt_transpose, gw, dim3(256), 0, stream, Wv, Wtv);
    hipLaunchKernelGGL((gemm_bf16<0>), gg, dim3(256), 0, stream, K, Wtk, bk, kh, 0.125f);
    hipLaunchKernelGGL((gemm_bf16<0>), gg, dim3(256), 0, stream, V, Wtv, bv, vh, 1.0f);
    hipLaunchKernelGGL(kv_partial, dim3(32, 16), dim3(256), 0, stream, kh, vh, proj, KVp, Zp);
    hipLaunchKernelGGL(kv_reduce, dim3(2048), dim3(256), 0, stream, KVp, Zp, KV, Z);
    hipLaunchKernelGGL(wcvt_transpose, gw, dim3(256), 0, stream, Wq, Wtq);
    hipLaunchKernelGGL((gemm_bf16<0>), gg, dim3(256), 0, stream, Q, Wtq, bq, qh, 0.125f);
    hipLaunchKernelGGL(qnum, dim3(32, 64), dim3(256), 0, stream, qh, proj, KV, Z, attn);
    hipLaunchKernelGGL(wcvt_transpose, gw, dim3(256), 0, stream, Wo, Wto);
    hipLaunchKernelGGL((gemm_bf16<1>), gg, dim3(256), 0, stream, attn, Wto, bo, out, 1.0f);
}

// Round 10
// 578.206 us; speedup vs baseline: 1.6740x; 1.6740x over previous
//
#include <hip/hip_runtime.h>
#include <hip/hip_bf16.h>
#include <math.h>

#define D_MODEL 1024
#define NH 16
#define DK 64
#define MF 256
#define LSEQ 4096
#define NB 2
#define BL (NB*LSEQ)   // 8192

typedef __attribute__((ext_vector_type(8))) short short8;
typedef __attribute__((ext_vector_type(4))) float f32x4;

static __device__ __forceinline__ unsigned short f2bf(float x) {
    return __builtin_bit_cast(unsigned short, __float2bfloat16(x));
}

// ---------------------------------------------------------------------------
// fp32 -> bf16 flat convert (8 elems/thread), for GEMM A operands
// ---------------------------------------------------------------------------
__global__ __launch_bounds__(256)
void acvt(const float* __restrict__ A, unsigned short* __restrict__ Ab)
{
    const size_t i = ((size_t)blockIdx.x * 256 + threadIdx.x) * 8;
    float4 x0 = *(const float4*)&A[i];
    float4 x1 = *(const float4*)&A[i + 4];
    short8 o;
    o[0] = (short)f2bf(x0.x); o[1] = (short)f2bf(x0.y);
    o[2] = (short)f2bf(x0.z); o[3] = (short)f2bf(x0.w);
    o[4] = (short)f2bf(x1.x); o[5] = (short)f2bf(x1.y);
    o[6] = (short)f2bf(x1.z); o[7] = (short)f2bf(x1.w);
    *(short8*)&Ab[i] = o;
}

// ---------------------------------------------------------------------------
// W[k][n] fp32 -> Wt[n][k] bf16 (transpose + convert), 32x32 tiles
// ---------------------------------------------------------------------------
__global__ __launch_bounds__(256)
void wcvt_transpose(const float* __restrict__ W, unsigned short* __restrict__ Wt)
{
    __shared__ float tile[32][33];
    const int t  = threadIdx.x;
    const int k0 = blockIdx.x * 32;
    const int n0 = blockIdx.y * 32;
    const int r  = t >> 3;
    const int c4 = (t & 7) * 4;
    *(float4*)&tile[r][c4] = *(const float4*)&W[(size_t)(k0 + r) * D_MODEL + n0 + c4];
    __syncthreads();
    ushort4 o;
    o.x = f2bf(tile[c4 + 0][r]);
    o.y = f2bf(tile[c4 + 1][r]);
    o.z = f2bf(tile[c4 + 2][r]);
    o.w = f2bf(tile[c4 + 3][r]);
    *(ushort4*)&Wt[(size_t)(n0 + r) * D_MODEL + k0 + c4] = o;
}

// ---------------------------------------------------------------------------
// bf16 MFMA GEMM: C[8192][1024] = Ab_bf16 @ Wt_bf16[n][k]^T (+bias)
// MODE 0: head-major (B,H,L,DK) write with scale
// MODE 1: row-major (BL,D) + bias
// MODE 2: head-DK-major (B,H,DK,L) with scale (transposed V for kv MFMA)
// 128x128 tile, 4 waves, each wave 64x64 = 4x4 frags of 16x16x32.
// ---------------------------------------------------------------------------
#define GBK 32
#define LDST 40

template<int MODE>
__global__ __launch_bounds__(256)
void gemm_bf16(const unsigned short* __restrict__ A, const unsigned short* __restrict__ Bt,
               const float* __restrict__ bias, float* __restrict__ out, float scale)
{
    __shared__ unsigned short As[128][LDST];   // [m][k]
    __shared__ unsigned short Bs[128][LDST];   // [n][k]
    const int t    = threadIdx.x;
    const int lane = t & 63;
    const int w    = t >> 6;
    const int wrow = (w >> 1) * 64;
    const int wcol = (w & 1) * 64;
    const int m0   = blockIdx.x * 128;
    const int n0   = blockIdx.y * 128;

    const int sr  = t & 127;    // staging row (m for A, n for B)
    const int skh = t >> 7;     // k-half: 16 elements

    f32x4 acc[4][4];
    #pragma unroll
    for (int i = 0; i < 4; i++)
        #pragma unroll
        for (int j = 0; j < 4; j++)
            acc[i][j] = (f32x4){0.f, 0.f, 0.f, 0.f};

    const unsigned short* ap = A  + (size_t)(m0 + sr) * D_MODEL + skh * 16;
    const unsigned short* bp = Bt + (size_t)(n0 + sr) * D_MODEL + skh * 16;

    for (int k0 = 0; k0 < D_MODEL; k0 += GBK) {
        short8 va0 = *(const short8*)(ap + k0 + 0);
        short8 va1 = *(const short8*)(ap + k0 + 8);
        *(short8*)&As[sr][skh * 16 + 0] = va0;
        *(short8*)&As[sr][skh * 16 + 8] = va1;
        short8 vb0 = *(const short8*)(bp + k0 + 0);
        short8 vb1 = *(const short8*)(bp + k0 + 8);
        *(short8*)&Bs[sr][skh * 16 + 0] = vb0;
        *(short8*)&Bs[sr][skh * 16 + 8] = vb1;
        __syncthreads();

        short8 af[4], bfr[4];
        #pragma unroll
        for (int i = 0; i < 4; i++) {
            af[i]  = *(const short8*)&As[wrow + i * 16 + (lane & 15)][(lane >> 4) * 8];
            bfr[i] = *(const short8*)&Bs[wcol + i * 16 + (lane & 15)][(lane >> 4) * 8];
        }
        #pragma unroll
        for (int mr = 0; mr < 4; mr++)
            #pragma unroll
            for (int nc = 0; nc < 4; nc++)
                acc[mr][nc] = __builtin_amdgcn_mfma_f32_16x16x32_bf16(
                    af[mr], bfr[nc], acc[mr][nc], 0, 0, 0);
        __syncthreads();
    }

    // epilogue: C/D frag mapping col=lane&15, row=(lane>>4)*4+reg (m89/m91)
    const int crow = (lane >> 4) * 4;
    const int ccol = lane & 15;
    #pragma unroll
    for (int nc = 0; nc < 4; nc++) {
        const int gcol = n0 + wcol + nc * 16 + ccol;
        const float bb = bias[gcol];
        #pragma unroll
        for (int mr = 0; mr < 4; mr++) {
            if (MODE == 2) {
                const int grow0 = m0 + wrow + mr * 16 + crow;   // 4-aligned
                const int b = grow0 >> 12;
                const int l = grow0 & (LSEQ - 1);
                const int h = gcol >> 6;
                const int c = gcol & 63;
                float4 o = make_float4((acc[mr][nc][0] + bb) * scale,
                                       (acc[mr][nc][1] + bb) * scale,
                                       (acc[mr][nc][2] + bb) * scale,
                                       (acc[mr][nc][3] + bb) * scale);
                *(float4*)&out[((size_t)(b * NH + h) * DK + c) * LSEQ + l] = o;
            } else {
                #pragma unroll
                for (int r = 0; r < 4; r++) {
                    const int grow = m0 + wrow + mr * 16 + crow + r;
                    const float v = acc[mr][nc][r] + bb;
                    if (MODE == 0) {
                        const int b = grow >> 12;
                        const int l = grow & (LSEQ - 1);
                        const int h = gcol >> 6;
                        const int c = gcol & 63;
                        out[((size_t)(b * NH + h) * LSEQ + l) * DK + c] = v * scale;
                    } else {
                        out[(size_t)grow * D_MODEL + gcol] = v;
                    }
                }
            }
        }
    }
}

// ---------------------------------------------------------------------------
// kv_partial MFMA: per (bh, 256-L chunk):
//   phase1: RFT[m][l] = P[m]. kh[l]   (MFMA, P persistent in regs)
//   kf = exp(rft) -> bf16 -> wave-private LDS [m][l]
//   phase2: KV[m][d] += Kf^T @ vh  via mfma(kf-frag, vhT-frag)
//   Z folded as ones-column of vhT (rows 64..79: row64=1, rest 0)
// kh LDS XOR-swizzled (128B rows); vhT stride 72 ush; kfs stride 40 ush.
// ---------------------------------------------------------------------------
__global__ __launch_bounds__(256)
void kv_partial_mfma(const float* __restrict__ kh, const float* __restrict__ vhT,
                     const float* __restrict__ proj, float* __restrict__ KVp,
                     float* __restrict__ Zp)
{
    const int bh    = blockIdx.x;
    const int h     = bh & (NH - 1);
    const int chunk = blockIdx.y;
    const int t     = threadIdx.x;
    const int lane  = t & 63;
    const int w     = t >> 6;
    const int wm0   = w * 64;
    const int g     = lane >> 4;    // k-group 0..3
    const int lr    = lane & 15;    // row-in-tile

    __shared__ unsigned short khs[32 * 64];    // [l][d] swizzled, 4 KB
    __shared__ unsigned short vhs[80 * 72];    // [d'][l] stride 72, 11.5 KB
    __shared__ unsigned short kfs[256 * 40];   // [m][l] stride 40, 20.5 KB

    // persistent P fragments (A-operand): pf[i][s] = P[wm0+i*16+lr][s*32+g*8 ..+8]
    short8 pf[4][2];
    {
        const float* Ph = proj + (size_t)h * (MF * DK);
        #pragma unroll
        for (int i = 0; i < 4; i++)
            #pragma unroll
            for (int s = 0; s < 2; s++) {
                const float* src = Ph + (size_t)(wm0 + i * 16 + lr) * DK + s * 32 + g * 8;
                float4 x0 = *(const float4*)src;
                float4 x1 = *(const float4*)(src + 4);
                short8 o;
                o[0] = (short)f2bf(x0.x); o[1] = (short)f2bf(x0.y);
                o[2] = (short)f2bf(x0.z); o[3] = (short)f2bf(x0.w);
                o[4] = (short)f2bf(x1.x); o[5] = (short)f2bf(x1.y);
                o[6] = (short)f2bf(x1.z); o[7] = (short)f2bf(x1.w);
                pf[i][s] = o;
            }
    }
    // init vhT ones/zero rows 64..79 (written once)
    if (t < 64) {
        int row = 64 + (t >> 2), l8 = (t & 3) * 8;
        unsigned short v = (row == 64) ? (unsigned short)0x3F80 : (unsigned short)0;
        short8 o;
        #pragma unroll
        for (int e = 0; e < 8; e++) o[e] = (short)v;
        *(short8*)&vhs[row * 72 + l8] = o;
    }

    f32x4 kv[4][5];
    #pragma unroll
    for (int i = 0; i < 4; i++)
        #pragma unroll
        for (int n = 0; n < 5; n++)
            kv[i][n] = (f32x4){0.f, 0.f, 0.f, 0.f};

    const float* khb = kh  + ((size_t)bh * LSEQ + chunk * 256) * DK;
    const float* vtb = vhT + ((size_t)bh * DK) * LSEQ + chunk * 256;

    for (int sub = 0; sub < 8; sub++) {
        __syncthreads();   // protect khs/vhs from previous-iter readers
        // stage kh 32x64 -> bf16, XOR-swizzled
        {
            int row = t >> 3, c8 = (t & 7) * 8;
            const float* src = khb + (size_t)(sub * 32 + row) * DK + c8;
            float4 x0 = *(const float4*)src;
            float4 x1 = *(const float4*)(src + 4);
            short8 o;
            o[0] = (short)f2bf(x0.x); o[1] = (short)f2bf(x0.y);
            o[2] = (short)f2bf(x0.z); o[3] = (short)f2bf(x0.w);
            o[4] = (short)f2bf(x1.x); o[5] = (short)f2bf(x1.y);
            o[6] = (short)f2bf(x1.z); o[7] = (short)f2bf(x1.w);
            int byte = row * 128 + c8 * 2;
            byte ^= (row & 7) << 4;
            *(short8*)((char*)khs + byte) = o;
        }
        // stage vhT rows 0..63 (d-major global, coalesced per d-row)
        {
            int d = t >> 2, l8 = (t & 3) * 8;
            const float* src = vtb + (size_t)d * LSEQ + sub * 32 + l8;
            float4 x0 = *(const float4*)src;
            float4 x1 = *(const float4*)(src + 4);
            short8 o;
            o[0] = (short)f2bf(x0.x); o[1] = (short)f2bf(x0.y);
            o[2] = (short)f2bf(x0.z); o[3] = (short)f2bf(x0.w);
            o[4] = (short)f2bf(x1.x); o[5] = (short)f2bf(x1.y);
            o[6] = (short)f2bf(x1.z); o[7] = (short)f2bf(x1.w);
            *(short8*)&vhs[d * 72 + l8] = o;
        }
        __syncthreads();

        // phase 1: rft[i][j] = P . kh^T
        f32x4 rft[4][2];
        #pragma unroll
        for (int i = 0; i < 4; i++)
            #pragma unroll
            for (int j = 0; j < 2; j++)
                rft[i][j] = (f32x4){0.f, 0.f, 0.f, 0.f};
        short8 khf[2][2];
        #pragma unroll
        for (int j = 0; j < 2; j++)
            #pragma unroll
            for (int s = 0; s < 2; s++) {
                int row = j * 16 + lr;
                int byte = row * 128 + s * 64 + g * 16;
                byte ^= (row & 7) << 4;
                khf[j][s] = *(short8*)((char*)khs + byte);
            }
        #pragma unroll
        for (int i = 0; i < 4; i++)
            #pragma unroll
            for (int j = 0; j < 2; j++)
                #pragma unroll
                for (int s = 0; s < 2; s++)
                    rft[i][j] = __builtin_amdgcn_mfma_f32_16x16x32_bf16(
                        pf[i][s], khf[j][s], rft[i][j], 0, 0, 0);

        // exp -> bf16 -> wave-private kfs[m][l]
        #pragma unroll
        for (int i = 0; i < 4; i++)
            #pragma unroll
            for (int j = 0; j < 2; j++)
                #pragma unroll
                for (int r = 0; r < 4; r++) {
                    float kfv = __expf(rft[i][j][r]);
                    int m = wm0 + i * 16 + g * 4 + r;
                    int l = j * 16 + lr;
                    kfs[m * 40 + l] = f2bf(kfv);
                }
        // phase 2 (kfs region is wave-private: no block barrier needed)
        #pragma unroll
        for (int i = 0; i < 4; i++) {
            short8 xf = *(short8*)&kfs[(wm0 + i * 16 + lr) * 40 + g * 8];
            #pragma unroll
            for (int n = 0; n < 5; n++) {
                short8 yf = *(short8*)&vhs[(n * 16 + lr) * 72 + g * 8];
                kv[i][n] = __builtin_amdgcn_mfma_f32_16x16x32_bf16(
                    xf, yf, kv[i][n], 0, 0, 0);
            }
        }
    }

    // write partials: KVp [chunk*32+bh][m][d], Zp [chunk*32+bh][m]
    float* kvb = KVp + ((size_t)(chunk * 32 + bh)) * (MF * DK);
    #pragma unroll
    for (int i = 0; i < 4; i++)
        #pragma unroll
        for (int n = 0; n < 4; n++)
            #pragma unroll
            for (int r = 0; r < 4; r++)
                kvb[(size_t)(wm0 + i * 16 + g * 4 + r) * DK + n * 16 + lr] = kv[i][n][r];
    if (lr == 0) {
        float* zb = Zp + ((size_t)(chunk * 32 + bh)) * MF;
        #pragma unroll
        for (int i = 0; i < 4; i++)
            #pragma unroll
            for (int r = 0; r < 4; r++)
                zb[wm0 + i * 16 + g * 4 + r] = kv[i][4][r];
    }
}

// Reduce 16 L-chunk partials -> KV (32*256*64) and Z (32*256)
__global__ __launch_bounds__(256)
void kv_reduce(const float* __restrict__ KVp, const float* __restrict__ Zp,
               float* __restrict__ KV, float* __restrict__ Z)
{
    const size_t i = (size_t)blockIdx.x * 256 + threadIdx.x;  // < 524288
    float s = 0.f;
    #pragma unroll
    for (int c = 0; c < 16; c++) s += KVp[(size_t)c * 524288 + i];
    KV[i] = s;
    if (i < 32 * MF) {
        float z = 0.f;
        #pragma unroll
        for (int c = 0; c < 16; c++) z += Zp[(size_t)c * 8192 + i];
        Z[i] = z;
    }
}

// ---------------------------------------------------------------------------
// qnum v3: Qf = exp(qh@proj^T)/16; num = Qf@KV; den = Qf@Z + eps
// Block = (b,h) x 64 L-rows. Thread owns rows {lo, lo+32} x 8 dk.
// ---------------------------------------------------------------------------
__global__ __launch_bounds__(256)
void qnum(const float* __restrict__ qh, const float* __restrict__ proj,
          const float* __restrict__ KV, const float* __restrict__ Z,
          float* __restrict__ attn)
{
    const int bh = blockIdx.x;
    const int h  = bh & (NH - 1);
    const int b  = bh >> 4;
    const int l0 = blockIdx.y * 64;
    const int t  = threadIdx.x;

    __shared__ float qfs[64][MF + 8];
    __shared__ float shU[32][64];
    __shared__ float Zs[MF];

    float4 pr[16];
    {
        const float4* pp = (const float4*)(proj + ((size_t)h * MF + t) * DK);
        #pragma unroll
        for (int i = 0; i < 16; i++) pr[i] = pp[i];
    }
    Zs[t] = Z[(size_t)bh * MF + t];

    #pragma unroll
    for (int half = 0; half < 2; half++) {
        const float* qhb = qh + ((size_t)bh * LSEQ + l0 + half * 32) * DK;
        #pragma unroll
        for (int i = 0; i < 2; i++) {
            int idx = t + 256 * i;
            int r  = idx >> 4;
            int c4 = (idx & 15) * 4;
            *(float4*)&shU[r][c4] = *(const float4*)&qhb[(size_t)r * DK + c4];
        }
        __syncthreads();
        #pragma unroll 4
        for (int l = 0; l < 32; l++) {
            float rf = 0.f;
            const float4* qr = (const float4*)shU[l];
            #pragma unroll
            for (int i = 0; i < 16; i++) {
                float4 q4 = qr[i];
                rf += q4.x * pr[i].x + q4.y * pr[i].y + q4.z * pr[i].z + q4.w * pr[i].w;
            }
            qfs[half * 32 + l][t] = __expf(rf) * 0.0625f;
        }
        __syncthreads();
    }

    const int lo  = t >> 3;
    const int dk0 = (t & 7) * 8;
    const float* KVb = KV + (size_t)bh * (MF * DK);
    float a0[8], a1[8];
    #pragma unroll
    for (int i = 0; i < 8; i++) { a0[i] = 0.f; a1[i] = 0.f; }
    float den0 = 0.f, den1 = 0.f;

    for (int mc = 0; mc < MF; mc += 32) {
        #pragma unroll
        for (int i = 0; i < 2; i++) {
            int idx = t + 256 * i;
            int r  = idx >> 4;
            int c4 = (idx & 15) * 4;
            *(float4*)&shU[r][c4] = *(const float4*)&KVb[(size_t)(mc + r) * DK + c4];
        }
        __syncthreads();
        #pragma unroll 8
        for (int mm = 0; mm < 32; mm++) {
            float qf0 = qfs[lo][mc + mm];
            float qf1 = qfs[lo + 32][mc + mm];
            float zz  = Zs[mc + mm];
            float4 k1 = *(const float4*)&shU[mm][dk0];
            float4 k2 = *(const float4*)&shU[mm][dk0 + 4];
            den0 += qf0 * zz;
            den1 += qf1 * zz;
            a0[0] += qf0 * k1.x; a0[1] += qf0 * k1.y; a0[2] += qf0 * k1.z; a0[3] += qf0 * k1.w;
            a0[4] += qf0 * k2.x; a0[5] += qf0 * k2.y; a0[6] += qf0 * k2.z; a0[7] += qf0 * k2.w;
            a1[0] += qf1 * k1.x; a1[1] += qf1 * k1.y; a1[2] += qf1 * k1.z; a1[3] += qf1 * k1.w;
            a1[4] += qf1 * k2.x; a1[5] += qf1 * k2.y; a1[6] += qf1 * k2.z; a1[7] += qf1 * k2.w;
        }
        __syncthreads();
    }

    const float inv0 = 1.f / (den0 + 1e-6f);
    const float inv1 = 1.f / (den1 + 1e-6f);
    float* op0 = attn + (((size_t)b * LSEQ + (l0 + lo)) * NH + h) * DK + dk0;
    float* op1 = attn + (((size_t)b * LSEQ + (l0 + lo + 32)) * NH + h) * DK + dk0;
    *(float4*)op0       = make_float4(a0[0]*inv0, a0[1]*inv0, a0[2]*inv0, a0[3]*inv0);
    *(float4*)(op0 + 4) = make_float4(a0[4]*inv0, a0[5]*inv0, a0[6]*inv0, a0[7]*inv0);
    *(float4*)op1       = make_float4(a1[0]*inv1, a1[1]*inv1, a1[2]*inv1, a1[3]*inv1);
    *(float4*)(op1 + 4) = make_float4(a1[4]*inv1, a1[5]*inv1, a1[6]*inv1, a1[7]*inv1);
}

// ---------------------------------------------------------------------------
extern "C" void kernel_launch(void* const* d_in, const int* in_sizes, int n_in,
                              void* d_out, int out_size, void* d_ws, size_t ws_size,
                              hipStream_t stream)
{
    (void)in_sizes; (void)n_in; (void)out_size;
    const float* Q    = (const float*)d_in[0];
    const float* K    = (const float*)d_in[1];
    const float* V    = (const float*)d_in[2];
    const float* Wq   = (const float*)d_in[3];
    const float* bq   = (const float*)d_in[4];
    const float* Wk   = (const float*)d_in[5];
    const float* bk   = (const float*)d_in[6];
    const float* Wv   = (const float*)d_in[7];
    const float* bv   = (const float*)d_in[8];
    const float* Wo   = (const float*)d_in[9];
    const float* bo   = (const float*)d_in[10];
    const float* proj = (const float*)d_in[11];
    float* out = (float*)d_out;
    float* ws  = (float*)d_ws;

    // workspace (float offsets), peak ~111.7 MB (layout of the round-7 PASS):
    float* kh   = ws;                  // 8388608; -> AbfB (Q bf16) -> attn
    float* vhT  = ws +  8388608;       // 8388608 (B,H,DK,L); -> AbfC (attn bf16)
    float* KVp  = ws + 16777216;       // 8388608; AbfA (K/V bf16) -> KVp -> qh
    float* Zp   = ws + 25165824;       // 131072
    float* KV   = ws + 25296896;       // 524288
    float* Z    = ws + 25821184;       // 8192
    unsigned short* Wtk = (unsigned short*)(ws + 25829376);
    unsigned short* Wtv = (unsigned short*)(ws + 26353664);
    unsigned short* Wtq = (unsigned short*)(ws + 26877952);
    unsigned short* Wto = (unsigned short*)(ws + 27402240);
    unsigned short* AbfA = (unsigned short*)KVp;  // dead before kv_partial writes
    unsigned short* AbfB = (unsigned short*)kh;   // kh dead after kv_partial
    unsigned short* AbfC = (unsigned short*)vhT;  // vhT dead after kv_partial
    float* qh   = KVp;                 // KVp dead after kv_reduce
    float* attn = kh;                  // AbfB dead after Q-gemm
    if (ws_size < (size_t)27926528 * sizeof(float)) return;  // guard

    const dim3 gw(32, 32);                   // W transpose tiles
    const dim3 gg(BL / 128, D_MODEL / 128);  // 64 x 8
    const dim3 ga(4096);                     // acvt: 8.4M elems / 8 / 256

    hipLaunchKernelGGL(acvt, ga, dim3(256), 0, stream, K, AbfA);
    hipLaunchKernelGGL(wcvt_transpose, gw, dim3(256), 0, stream, Wk, Wtk);
    hipLaunchKernelGGL((gemm_bf16<0>), gg, dim3(256), 0, stream, AbfA, Wtk, bk, kh, 0.125f);
    hipLaunchKernelGGL(acvt, ga, dim3(256), 0, stream, V, AbfA);
    hipLaunchKernelGGL(wcvt_transpose, gw, dim3(256), 0, stream, Wv, Wtv);
    hipLaunchKernelGGL((gemm_bf16<2>), gg, dim3(256), 0, stream, AbfA, Wtv, bv, vhT, 1.0f);
    hipLaunchKernelGGL(kv_partial_mfma, dim3(32, 16), dim3(256), 0, stream, kh, vhT, proj, KVp, Zp);
    hipLaunchKernelGGL(kv_reduce, dim3(2048), dim3(256), 0, stream, KVp, Zp, KV, Z);
    hipLaunchKernelGGL(acvt, ga, dim3(256), 0, stream, Q, AbfB);
    hipLaunchKernelGGL(wcvt_transpose, gw, dim3(256), 0, stream, Wq, Wtq);
    hipLaunchKernelGGL((gemm_bf16<0>), gg, dim3(256), 0, stream, AbfB, Wtq, bq, qh, 0.125f);
    hipLaunchKernelGGL(qnum, dim3(32, 64), dim3(256), 0, stream, qh, proj, KV, Z, attn);
    hipLaunchKernelGGL(acvt, ga, dim3(256), 0, stream, attn, AbfC);
    hipLaunchKernelGGL(wcvt_transpose, gw, dim3(256), 0, stream, Wo, Wto);
    hipLaunchKernelGGL((gemm_bf16<1>), gg, dim3(256), 0, stream, AbfC, Wto, bo, out, 1.0f);
}